// Round 7
// baseline (578.725 us; speedup 1.0000x reference)
//
#include <hip/hip_runtime.h>
#include <hip/hip_bf16.h>
#include <cstdint>

#define M_ROWS 16384

typedef __attribute__((ext_vector_type(8))) short short8;
typedef __attribute__((ext_vector_type(4))) float f32x4;
typedef __attribute__((ext_vector_type(2))) float f32x2;

__device__ __forceinline__ unsigned long long umin64(unsigned long long a,
                                                     unsigned long long b) {
  return a < b ? a : b;
}

// ---------------------------------------------------------------------------
// fp32 GEMM (SA1/SA2 — feeds masks, bit-identical path).
// ---------------------------------------------------------------------------
__global__ __launch_bounds__(256) void gemm_bias_relu(
    const float* __restrict__ X, int ldx,
    const float* __restrict__ W,
    const float* __restrict__ bias,
    float* __restrict__ Y, int ldy,
    int N, int K)
{
  __shared__ __align__(16) float As[16][68];
  __shared__ __align__(16) float Bs[16][68];
  int tid = threadIdx.x;
  int tx = tid & 15, ty = tid >> 4;
  int m0 = blockIdx.y << 6, n0 = blockIdx.x << 6;
  float acc[4][4] = {};
  for (int k0 = 0; k0 < K; k0 += 16) {
#pragma unroll
    for (int i = 0; i < 4; i++) {
      int idx = tid + (i << 8);
      int m = idx >> 4, k = idx & 15;
      As[k][m] = (k0 + k < K) ? X[(size_t)(m0 + m) * ldx + k0 + k] : 0.f;
    }
#pragma unroll
    for (int i = 0; i < 4; i++) {
      int idx = tid + (i << 8);
      int n = idx & 63, k = idx >> 6;
      Bs[k][n] = (k0 + k < K) ? W[(size_t)(k0 + k) * N + n0 + n] : 0.f;
    }
    __syncthreads();
#pragma unroll
    for (int k = 0; k < 16; k++) {
      float4 a4 = *(const float4*)&As[k][ty << 2];
      float4 b4 = *(const float4*)&Bs[k][tx << 2];
      float av[4] = {a4.x, a4.y, a4.z, a4.w};
      float bv[4] = {b4.x, b4.y, b4.z, b4.w};
#pragma unroll
      for (int i = 0; i < 4; i++)
#pragma unroll
        for (int j = 0; j < 4; j++)
          acc[i][j] += av[i] * bv[j];
    }
    __syncthreads();
  }
  float4 bb = *(const float4*)&bias[n0 + (tx << 2)];
  float bv[4] = {bb.x, bb.y, bb.z, bb.w};
#pragma unroll
  for (int i = 0; i < 4; i++) {
    int m = m0 + (ty << 2) + i;
    float4 o;
    o.x = fmaxf(acc[i][0] + bv[0], 0.f);
    o.y = fmaxf(acc[i][1] + bv[1], 0.f);
    o.z = fmaxf(acc[i][2] + bv[2], 0.f);
    o.w = fmaxf(acc[i][3] + bv[3], 0.f);
    *(float4*)&Y[(size_t)m * ldy + n0 + (tx << 2)] = o;
  }
}

// ---------------------------------------------------------------------------
// Fused weight prep: 8 transposes (W KxN fp32 -> Wt NxK bf16) in one dispatch.
// ---------------------------------------------------------------------------
struct TJobs {
  const float* W[8];
  __hip_bfloat16* Wt[8];
  int K[8], N[8], bx[8], off[8];
};

__global__ __launch_bounds__(256) void transpose_cast_all(TJobs jb)
{
  __shared__ float tile[32][33];
  int bid = blockIdx.x;
  int j = 0;
#pragma unroll
  for (int t = 1; t < 8; t++)
    if (bid >= jb.off[t]) j = t;
  int rel = bid - jb.off[j];
  int K = jb.K[j], N = jb.N[j];
  const float* W = jb.W[j];
  __hip_bfloat16* Wt = jb.Wt[j];
  int n0 = (rel % jb.bx[j]) << 5, k0 = (rel / jb.bx[j]) << 5;
  int c = threadIdx.x & 31, i0 = threadIdx.x >> 5;
#pragma unroll
  for (int p = 0; p < 4; p++) {
    int i = i0 + p * 8;
    tile[i][c] = W[(size_t)(k0 + i) * N + n0 + c];
  }
  __syncthreads();
#pragma unroll
  for (int p = 0; p < 4; p++) {
    int r = i0 + p * 8;
    Wt[(size_t)(n0 + r) * K + k0 + c] = (__hip_bfloat16)tile[c][r];
  }
}

// ---------------------------------------------------------------------------
// bf16 MFMA GEMM (unchanged).
// ---------------------------------------------------------------------------
template <bool OUT_BF16>
__global__ __launch_bounds__(256) void gemm_mfma(
    const __hip_bfloat16* __restrict__ A, int lda,
    const __hip_bfloat16* __restrict__ Wt, int ldw,
    const float* __restrict__ bias,
    void* __restrict__ Y, int ldy, int N, int K)
{
  __shared__ __align__(16) short As[128][40];
  __shared__ __align__(16) short Bs[128][40];
  int tid = threadIdx.x;
  int wave = tid >> 6, lane = tid & 63;
  int quad = lane >> 4, l16 = lane & 15;
  int m0 = blockIdx.y << 7, n0 = blockIdx.x << 7;
  int wm = (wave >> 1) << 6, wn = (wave & 1) << 6;
  f32x4 acc[4][4] = {};
  const short* Ag = (const short*)A;
  const short* Bg = (const short*)Wt;
  int srow = tid >> 2, sq = tid & 3;
  for (int k0 = 0; k0 < K; k0 += 32) {
#pragma unroll
    for (int h = 0; h < 2; h++) {
      int r = srow + (h << 6);
      uint4 va = *(const uint4*)&Ag[(size_t)(m0 + r) * lda + k0 + sq * 8];
      *(uint4*)&As[r][sq * 8] = va;
      uint4 vb = *(const uint4*)&Bg[(size_t)(n0 + r) * ldw + k0 + sq * 8];
      *(uint4*)&Bs[r][sq * 8] = vb;
    }
    __syncthreads();
    short8 a[4], b[4];
#pragma unroll
    for (int mi = 0; mi < 4; mi++)
      a[mi] = *(const short8*)&As[wm + mi * 16 + l16][quad * 8];
#pragma unroll
    for (int ni = 0; ni < 4; ni++)
      b[ni] = *(const short8*)&Bs[wn + ni * 16 + l16][quad * 8];
#pragma unroll
    for (int mi = 0; mi < 4; mi++)
#pragma unroll
      for (int ni = 0; ni < 4; ni++)
        acc[mi][ni] = __builtin_amdgcn_mfma_f32_16x16x32_bf16(
            a[mi], b[ni], acc[mi][ni], 0, 0, 0);
    __syncthreads();
  }
  float bn[4];
#pragma unroll
  for (int ni = 0; ni < 4; ni++) bn[ni] = bias[n0 + wn + ni * 16 + l16];
#pragma unroll
  for (int mi = 0; mi < 4; mi++)
#pragma unroll
    for (int ni = 0; ni < 4; ni++) {
      int n = n0 + wn + ni * 16 + l16;
#pragma unroll
      for (int r = 0; r < 4; r++) {
        int m = m0 + wm + mi * 16 + quad * 4 + r;
        float v = fmaxf(acc[mi][ni][r] + bn[ni], 0.f);
        if (OUT_BF16)
          ((__hip_bfloat16*)Y)[(size_t)m * ldy + n] = (__hip_bfloat16)v;
        else
          ((float*)Y)[(size_t)m * ldy + n] = v;
      }
    }
}

// ---------------------------------------------------------------------------
// fc2 + out head fused: out = sigmoid(relu(A@Wt^T + b) . wout + bout).
// M-tile 128 per block, N=128, K=256. Deterministic reduction: sum over ni
// in-register, shfl-xor over 16 lanes, 2 wave-halves summed via LDS slots.
// ---------------------------------------------------------------------------
__global__ __launch_bounds__(256) void gemm_fc2_out(
    const __hip_bfloat16* __restrict__ A,      // 16384 x 256
    const __hip_bfloat16* __restrict__ Wt,     // 128 x 256
    const float* __restrict__ bias,            // 128
    const float* __restrict__ wout,            // 128
    const float* __restrict__ bout,            // 1
    float* __restrict__ out)                   // 16384
{
  __shared__ __align__(16) short As[128][40];
  __shared__ __align__(16) short Bs[128][40];
  __shared__ float red[128][2];
  const int N = 128, K = 256, lda = 256, ldw = 256;
  int tid = threadIdx.x;
  int wave = tid >> 6, lane = tid & 63;
  int quad = lane >> 4, l16 = lane & 15;
  int m0 = blockIdx.y << 7;
  int wm = (wave >> 1) << 6, wn = (wave & 1) << 6;
  f32x4 acc[4][4] = {};
  const short* Ag = (const short*)A;
  const short* Bg = (const short*)Wt;
  int srow = tid >> 2, sq = tid & 3;
  for (int k0 = 0; k0 < K; k0 += 32) {
#pragma unroll
    for (int h = 0; h < 2; h++) {
      int r = srow + (h << 6);
      uint4 va = *(const uint4*)&Ag[(size_t)(m0 + r) * lda + k0 + sq * 8];
      *(uint4*)&As[r][sq * 8] = va;
      uint4 vb = *(const uint4*)&Bg[(size_t)(r % N) * ldw + k0 + sq * 8];
      *(uint4*)&Bs[r][sq * 8] = vb;
    }
    __syncthreads();
    short8 a[4], b[4];
#pragma unroll
    for (int mi = 0; mi < 4; mi++)
      a[mi] = *(const short8*)&As[wm + mi * 16 + l16][quad * 8];
#pragma unroll
    for (int ni = 0; ni < 4; ni++)
      b[ni] = *(const short8*)&Bs[wn + ni * 16 + l16][quad * 8];
#pragma unroll
    for (int mi = 0; mi < 4; mi++)
#pragma unroll
      for (int ni = 0; ni < 4; ni++)
        acc[mi][ni] = __builtin_amdgcn_mfma_f32_16x16x32_bf16(
            a[mi], b[ni], acc[mi][ni], 0, 0, 0);
    __syncthreads();
  }
  float bn[4], wo[4];
#pragma unroll
  for (int ni = 0; ni < 4; ni++) {
    int n = wn + ni * 16 + l16;
    bn[ni] = bias[n];
    wo[ni] = wout[n];
  }
  float sacc[4][4];
#pragma unroll
  for (int mi = 0; mi < 4; mi++)
#pragma unroll
    for (int r = 0; r < 4; r++) {
      float s = 0.f;
#pragma unroll
      for (int ni = 0; ni < 4; ni++)
        s += fmaxf(acc[mi][ni][r] + bn[ni], 0.f) * wo[ni];
      sacc[mi][r] = s;
    }
#pragma unroll
  for (int off = 1; off < 16; off <<= 1)
#pragma unroll
    for (int mi = 0; mi < 4; mi++)
#pragma unroll
      for (int r = 0; r < 4; r++)
        sacc[mi][r] += __shfl_xor(sacc[mi][r], off);
  int wp = wave & 1;
  if (l16 == 0) {
#pragma unroll
    for (int mi = 0; mi < 4; mi++)
#pragma unroll
      for (int r = 0; r < 4; r++)
        red[wm + mi * 16 + quad * 4 + r][wp] = sacc[mi][r];
  }
  __syncthreads();
  if (tid < 128) {
    float s = red[tid][0] + red[tid][1] + bout[0];
    out[(size_t)(m0 + tid)] = 1.f / (1.f + expf(-s));
  }
}

// ---------------------------------------------------------------------------
// SA1 KNN v4: per-wave shfl rank (no LDS broadcast loop). Threshold
// T' = min over waves of each wave's 32nd-smallest thread-min; T' >= global
// 32nd-smallest and the argmin wave contributes 32 keys <= T' -> >=32
// survivors, superset of top-32. Final O(s^2) rank-merge unchanged ->
// selected set and order bit-identical.
// ---------------------------------------------------------------------------
__global__ __launch_bounds__(256) void knn_mean_kernel(
    const float* __restrict__ X,
    const float* __restrict__ G1,
    float* __restrict__ X1,
    __hip_bfloat16* __restrict__ X1b)
{
  int q = blockIdx.x;
  int base = q & ~2047;
  int tid = threadIdx.x;
  int wave = tid >> 6;
  __shared__ unsigned long long surv[2048];
  __shared__ unsigned long long twave[4];
  __shared__ int scnt;
  __shared__ int selidx[32];
  if (tid == 0) scnt = 0;
  float qx = X[(size_t)q * 2], qy = X[(size_t)q * 2 + 1];
  unsigned long long key[8];
#pragma unroll
  for (int u = 0; u < 8; u++) {
    int j = (u << 8) + tid;
    float dx = X[(size_t)(base + j) * 2] - qx;
    float dy = X[(size_t)(base + j) * 2 + 1] - qy;
    float d2 = dx * dx + dy * dy;
    key[u] = ((unsigned long long)__float_as_uint(d2) << 32) | (unsigned)j;
  }
  unsigned long long lm = key[0];
#pragma unroll
  for (int u = 1; u < 8; u++) lm = umin64(lm, key[u]);
  // per-wave rank of lm among the wave's 64 thread-mins (unique keys)
  int rank = 0;
#pragma unroll
  for (int i = 0; i < 64; i++) {
    unsigned long long v = __shfl(lm, i);
    rank += (v < lm) ? 1 : 0;
  }
  if (rank == 31) twave[wave] = lm;  // exactly one lane per wave
  __syncthreads();
  unsigned long long T = umin64(umin64(twave[0], twave[1]),
                                umin64(twave[2], twave[3]));
#pragma unroll
  for (int u = 0; u < 8; u++) {
    if (key[u] <= T) {
      int p = atomicAdd(&scnt, 1);
      surv[p] = key[u];
    }
  }
  __syncthreads();
  int s = scnt;  // >= 32 guaranteed
  for (int i = tid; i < s; i += 256) {
    unsigned long long c = surv[i];
    int r = 0;
    for (int j2 = 0; j2 < s; j2++) r += (surv[j2] < c);
    if (r < 32) selidx[r] = (int)(c & 0xffffffffULL);
  }
  __syncthreads();
  if (tid < 64) {
    float acc = 0.f;
#pragma unroll 4
    for (int sI = 0; sI < 32; sI++)
      acc += G1[(size_t)(base + selidx[sI]) * 64 + tid];
    float v = acc * (1.0f / 32.0f);
    X1[(size_t)q * 64 + tid] = v;
    X1b[(size_t)q * 64 + tid] = (__hip_bfloat16)v;
  }
}

// ---------------------------------------------------------------------------
// Ball-query pass 1 v5 — symmetric + double-buffered k-tile staging (one
// sync per tile; global loads overlap compute). Inner packed-fp32 math and
// mask assembly identical to v4 -> masks bit-identical. NO min-occupancy
// launch bound (256,3 spilled the acc tile — 10x regression).
// ---------------------------------------------------------------------------
template <int C>
__global__ __launch_bounds__(256) void ball_mask_sym(
    const float* __restrict__ F,
    unsigned long long* __restrict__ mask,
    float r2)
{
  __shared__ __align__(16) float As[2][16][132];
  __shared__ __align__(16) float Bs[2][16][132];
  __shared__ unsigned int tw[128][4];  // transposed bits: [c-local][q-word32]
  int tid = threadIdx.x;
  int tx = tid & 15, ty = tid >> 4;
  int p = blockIdx.x;
  int qt = 0;
  while (p >= 16 - qt) { p -= 16 - qt; qt++; }
  int ct = qt + p;
  int b0 = blockIdx.y << 11;
  int q0 = b0 + (qt << 7), c0 = b0 + (ct << 7);
  tw[tid >> 2][tid & 3] = 0;
  tw[(tid + 256) >> 2][tid & 3] = 0;

  auto stage = [&](int k0, int buf) {
#pragma unroll
    for (int c = 0; c < 2; c++) {
      int idx = tid + (c << 8);
      int row = idx >> 2, qr = idx & 3;
      float4 va = *(const float4*)&F[(size_t)(q0 + row) * C + k0 + qr * 4];
      As[buf][qr * 4 + 0][row] = va.x;
      As[buf][qr * 4 + 1][row] = va.y;
      As[buf][qr * 4 + 2][row] = va.z;
      As[buf][qr * 4 + 3][row] = va.w;
      float4 vb = *(const float4*)&F[(size_t)(c0 + row) * C + k0 + qr * 4];
      Bs[buf][qr * 4 + 0][row] = vb.x;
      Bs[buf][qr * 4 + 1][row] = vb.y;
      Bs[buf][qr * 4 + 2][row] = vb.z;
      Bs[buf][qr * 4 + 3][row] = vb.w;
    }
  };

  constexpr int NT = C / 16;
  stage(0, 0);
  f32x2 acc2[8][4] = {};
  for (int t = 0; t < NT; t++) {
    __syncthreads();
    if (t + 1 < NT) stage((t + 1) << 4, (t + 1) & 1);
    int buf = t & 1;
#pragma unroll
    for (int k = 0; k < 16; k++) {
      float av[8];
      f32x2 bv2[4];
      *(float4*)&av[0] = *(const float4*)&As[buf][k][ty * 8];
      *(float4*)&av[4] = *(const float4*)&As[buf][k][ty * 8 + 4];
      *(float4*)&bv2[0] = *(const float4*)&Bs[buf][k][tx * 4];
      *(float4*)&bv2[2] = *(const float4*)&Bs[buf][k][64 + tx * 4];
#pragma unroll
      for (int i = 0; i < 8; i++) {
        f32x2 a2 = {av[i], av[i]};
#pragma unroll
        for (int j2 = 0; j2 < 4; j2++) {
          f32x2 d = a2 - bv2[j2];
          acc2[i][j2] += d * d;
        }
      }
    }
  }
  int w0 = ct << 1;
  unsigned int bytes[8] = {0, 0, 0, 0, 0, 0, 0, 0};
#pragma unroll
  for (int i = 0; i < 8; i++) {
    unsigned long long wlo = 0, whi = 0;
#pragma unroll
    for (int j = 0; j < 4; j++) {
      float dlo = acc2[i][j >> 1][j & 1];
      float dhi = acc2[i][2 + (j >> 1)][j & 1];
      if (dlo <= r2) { wlo |= 1ULL << (tx * 4 + j); bytes[j] |= 1u << i; }
      if (dhi <= r2) { whi |= 1ULL << (tx * 4 + j); bytes[4 + j] |= 1u << i; }
    }
#pragma unroll
    for (int s = 1; s <= 8; s <<= 1) {
      wlo |= __shfl_xor(wlo, s);
      whi |= __shfl_xor(whi, s);
    }
    if (tx == 0) {
      int q = q0 + ty * 8 + i;
      mask[(size_t)q * 32 + w0] = wlo;
      mask[(size_t)q * 32 + w0 + 1] = whi;
    }
  }
  if (qt != ct) {
    int sh = (ty & 3) * 8, wq = ty >> 2;
#pragma unroll
    for (int j2 = 0; j2 < 8; j2++) {
      int cl = ((j2 >> 2) << 6) + tx * 4 + (j2 & 3);
      atomicOr(&tw[cl][wq], bytes[j2] << sh);
    }
    __syncthreads();
    int row = tid >> 1, word = tid & 1;
    unsigned long long v = (unsigned long long)tw[row][word * 2] |
                           ((unsigned long long)tw[row][word * 2 + 1] << 32);
    mask[(size_t)(c0 + row) * 32 + (qt << 1) + word] = v;
  }
}

// ---------------------------------------------------------------------------
// Ball-query pass 2 (templated input dtype; fp32 accumulate).
// ---------------------------------------------------------------------------
template <typename TIn>
__global__ void ball_gather_kernel(
    const unsigned long long* __restrict__ mask,
    const TIn* __restrict__ H, int CH,
    float* __restrict__ Yf, __hip_bfloat16* __restrict__ Yb,
    int ldy, int S)
{
  int q = blockIdx.x;
  int base = q & ~2047;
  int tid = threadIdx.x;
  __shared__ int idxl[64];
  __shared__ float wtab[64];
  __shared__ int scount;
  if (tid < 32) {
    unsigned long long w = mask[(size_t)q * 32 + tid];
    int cnt = __popcll(w);
    int inc = cnt;
#pragma unroll
    for (int off = 1; off < 32; off <<= 1) {
      int o = __shfl_up(inc, off);
      if (tid >= off) inc += o;
    }
    if (tid == 31) scount = inc;
    int p = inc - cnt;
    while (w && p < 64) {
      int j = (tid << 6) + __builtin_ctzll(w);
      w &= w - 1;
      idxl[p++] = j;
    }
  }
  __syncthreads();
  int c = scount;
  if (tid < 64) {
    int p = tid;
    int cnt = (p < c && p < S) ? ((S - 1 - p) / c + 1) : 0;
    wtab[p] = (float)cnt / (float)S;
  }
  __syncthreads();
  float acc = 0.f;
  int lim = c < S ? c : S;
#pragma unroll 4
  for (int s = 0; s < lim; s++)
    acc += wtab[s] * (float)H[(size_t)(base + idxl[s]) * CH + tid];
  if (Yf) Yf[(size_t)q * ldy + tid] = acc;
  if (Yb) Yb[(size_t)q * ldy + tid] = (__hip_bfloat16)acc;
}

// ---------------------------------------------------------------------------
extern "C" void kernel_launch(void* const* d_in, const int* in_sizes, int n_in,
                              void* d_out, int out_size, void* d_ws,
                              size_t ws_size, hipStream_t stream)
{
  const float* x      = (const float*)d_in[0];
  const float* sa1_w0 = (const float*)d_in[1];
  const float* sa1_b0 = (const float*)d_in[2];
  const float* sa1_w1 = (const float*)d_in[3];
  const float* sa1_b1 = (const float*)d_in[4];
  const float* sa2_w0 = (const float*)d_in[5];
  const float* sa2_b0 = (const float*)d_in[6];
  const float* sa2_w1 = (const float*)d_in[7];
  const float* sa2_b1 = (const float*)d_in[8];
  const float* sa3_w0 = (const float*)d_in[9];
  const float* sa3_b0 = (const float*)d_in[10];
  const float* sa3_w1 = (const float*)d_in[11];
  const float* sa3_b1 = (const float*)d_in[12];
  const float* fp1_w0 = (const float*)d_in[13];
  const float* fp1_b0 = (const float*)d_in[14];
  const float* fp1_w1 = (const float*)d_in[15];
  const float* fp1_b1 = (const float*)d_in[16];
  const float* fp2_w0 = (const float*)d_in[17];
  const float* fp2_b0 = (const float*)d_in[18];
  const float* fp2_w1 = (const float*)d_in[19];
  const float* fp2_b1 = (const float*)d_in[20];
  const float* fc1_w  = (const float*)d_in[21];
  const float* fc1_b  = (const float*)d_in[22];
  const float* fc2_w  = (const float*)d_in[23];
  const float* fc2_b  = (const float*)d_in[24];
  const float* out_w  = (const float*)d_in[25];
  const float* out_b  = (const float*)d_in[26];
  float* out = (float*)d_out;

  const size_t M = M_ROWS;
  float* ws = (float*)d_ws;
  float* T   = ws;             // M*256
  float* G1  = ws + M * 256;   // M*64
  float* X1  = ws + M * 320;   // M*64
  float* X2  = ws + M * 384;   // M*128
  float* H2  = ws + M * 512;   // M*128 (sa2 out fp32)
  __hip_bfloat16* H3b16 = (__hip_bfloat16*)(ws + M * 640);  // M*256 bf16 (sa3 out)
  unsigned long long* MASK = (unsigned long long*)(ws + M * 896);  // M*32 u64
  __hip_bfloat16* X1b = (__hip_bfloat16*)(ws + M * 960);   // M*64
  __hip_bfloat16* X2b = (__hip_bfloat16*)(ws + M * 992);   // M*128
  __hip_bfloat16* TB  = (__hip_bfloat16*)(ws + M * 1056);  // M*512
  __hip_bfloat16* G   = (__hip_bfloat16*)(ws + M * 1312);  // M*1024
  __hip_bfloat16* H3b = (__hip_bfloat16*)(ws + M * 1824);  // M*256 (fc1 out)
  __hip_bfloat16* WB  = (__hip_bfloat16*)(ws + M * 1952);
  if (ws_size < (size_t)M * 1984 * sizeof(float)) return;
  __hip_bfloat16* w_sa3_0 = WB;               // 256x128
  __hip_bfloat16* w_sa3_1 = w_sa3_0 + 32768;  // 256x256
  __hip_bfloat16* w_fp1_0 = w_sa3_1 + 65536;  // 512x128
  __hip_bfloat16* w_fp1_1 = w_fp1_0 + 65536;  // 512x512
  __hip_bfloat16* w_fp2_0 = w_fp1_1 + 262144; // 256x64
  __hip_bfloat16* w_fp2_1 = w_fp2_0 + 16384;  // 256x256
  __hip_bfloat16* w_fc1   = w_fp2_1 + 65536;  // 256x1024
  __hip_bfloat16* w_fc2   = w_fc1 + 262144;   // 128x256

  dim3 blk(256);
  TJobs jb;
  const float* srcs[8] = {sa3_w0, sa3_w1, fp1_w0, fp1_w1, fp2_w0, fp2_w1, fc1_w, fc2_w};
  __hip_bfloat16* dsts[8] = {w_sa3_0, w_sa3_1, w_fp1_0, w_fp1_1, w_fp2_0, w_fp2_1, w_fc1, w_fc2};
  int Ks[8] = {128, 256, 128, 512, 64, 256, 1024, 256};
  int Ns[8] = {256, 256, 512, 512, 256, 256, 256, 128};
  int off = 0;
  for (int i = 0; i < 8; i++) {
    jb.W[i] = srcs[i]; jb.Wt[i] = dsts[i];
    jb.K[i] = Ks[i]; jb.N[i] = Ns[i];
    jb.bx[i] = Ns[i] >> 5;
    jb.off[i] = off;
    off += (Ns[i] >> 5) * (Ks[i] >> 5);
  }
  transpose_cast_all<<<off, blk, 0, stream>>>(jb);

  // SA1 (fp32 exact).
  gemm_bias_relu<<<dim3(1, 256), blk, 0, stream>>>(x, 2, sa1_w0, sa1_b0, T, 64, 64, 2);
  gemm_bias_relu<<<dim3(1, 256), blk, 0, stream>>>(T, 64, sa1_w1, sa1_b1, G1, 64, 64, 64);
  knn_mean_kernel<<<16384, 256, 0, stream>>>(x, G1, X1, X1b);
  // SA2 (fp32 exact).
  gemm_bias_relu<<<dim3(2, 256), blk, 0, stream>>>(X1, 64, sa2_w0, sa2_b0, T, 128, 128, 64);
  gemm_bias_relu<<<dim3(2, 256), blk, 0, stream>>>(T, 128, sa2_w1, sa2_b1, H2, 128, 128, 128);
  ball_mask_sym<64><<<dim3(136, 8), blk, 0, stream>>>(X1, MASK, 0.2f * 0.2f);
  ball_gather_kernel<float><<<16384, 128, 0, stream>>>(MASK, H2, 128, X2, X2b, 128, 32);
  // SA3 MLP (bf16 MFMA; output stored bf16 — only feeds bf16 G columns).
  gemm_mfma<true><<<dim3(2, 128), blk, 0, stream>>>(X2b, 128, w_sa3_0, 128, sa3_b0, TB, 256, 256, 128);
  gemm_mfma<true><<<dim3(2, 128), blk, 0, stream>>>(TB, 256, w_sa3_1, 256, sa3_b1, H3b16, 256, 256, 256);
  ball_mask_sym<128><<<dim3(136, 8), blk, 0, stream>>>(X2, MASK, 0.4f * 0.4f);
  ball_gather_kernel<__hip_bfloat16><<<16384, 256, 0, stream>>>(MASK, H3b16, 256, nullptr, G + 768, 1024, 64);
  // FP1 (bf16).
  gemm_mfma<true><<<dim3(4, 128), blk, 0, stream>>>(X2b, 128, w_fp1_0, 128, fp1_b0, TB, 512, 512, 128);
  gemm_mfma<true><<<dim3(4, 128), blk, 0, stream>>>(TB, 512, w_fp1_1, 512, fp1_b1, G + 256, 1024, 512, 512);
  // FP2 (bf16).
  gemm_mfma<true><<<dim3(2, 128), blk, 0, stream>>>(X1b, 64, w_fp2_0, 64, fp2_b0, TB, 256, 256, 64);
  gemm_mfma<true><<<dim3(2, 128), blk, 0, stream>>>(TB, 256, w_fp2_1, 256, fp2_b1, G, 1024, 256, 256);
  // Head: fc1 (bf16), then fc2+out fused.
  gemm_mfma<true><<<dim3(2, 128), blk, 0, stream>>>(G, 1024, w_fc1, 1024, fc1_b, H3b, 256, 256, 1024);
  gemm_fc2_out<<<dim3(1, 128), blk, 0, stream>>>(H3b, w_fc2, fc2_b, out_w, out_b, out);
}

// Round 8
// 520.265 us; speedup vs baseline: 1.1124x; 1.1124x over previous
//
#include <hip/hip_runtime.h>
#include <hip/hip_bf16.h>
#include <cstdint>

#define M_ROWS 16384

typedef __attribute__((ext_vector_type(8))) short short8;
typedef __attribute__((ext_vector_type(4))) float f32x4;
typedef __attribute__((ext_vector_type(2))) float f32x2;

__device__ __forceinline__ unsigned long long umin64(unsigned long long a,
                                                     unsigned long long b) {
  return a < b ? a : b;
}

// ---------------------------------------------------------------------------
// fp32 GEMM (SA1/SA2 — feeds masks, bit-identical path).
// ---------------------------------------------------------------------------
__global__ __launch_bounds__(256) void gemm_bias_relu(
    const float* __restrict__ X, int ldx,
    const float* __restrict__ W,
    const float* __restrict__ bias,
    float* __restrict__ Y, int ldy,
    int N, int K)
{
  __shared__ __align__(16) float As[16][68];
  __shared__ __align__(16) float Bs[16][68];
  int tid = threadIdx.x;
  int tx = tid & 15, ty = tid >> 4;
  int m0 = blockIdx.y << 6, n0 = blockIdx.x << 6;
  float acc[4][4] = {};
  for (int k0 = 0; k0 < K; k0 += 16) {
#pragma unroll
    for (int i = 0; i < 4; i++) {
      int idx = tid + (i << 8);
      int m = idx >> 4, k = idx & 15;
      As[k][m] = (k0 + k < K) ? X[(size_t)(m0 + m) * ldx + k0 + k] : 0.f;
    }
#pragma unroll
    for (int i = 0; i < 4; i++) {
      int idx = tid + (i << 8);
      int n = idx & 63, k = idx >> 6;
      Bs[k][n] = (k0 + k < K) ? W[(size_t)(k0 + k) * N + n0 + n] : 0.f;
    }
    __syncthreads();
#pragma unroll
    for (int k = 0; k < 16; k++) {
      float4 a4 = *(const float4*)&As[k][ty << 2];
      float4 b4 = *(const float4*)&Bs[k][tx << 2];
      float av[4] = {a4.x, a4.y, a4.z, a4.w};
      float bv[4] = {b4.x, b4.y, b4.z, b4.w};
#pragma unroll
      for (int i = 0; i < 4; i++)
#pragma unroll
        for (int j = 0; j < 4; j++)
          acc[i][j] += av[i] * bv[j];
    }
    __syncthreads();
  }
  float4 bb = *(const float4*)&bias[n0 + (tx << 2)];
  float bv[4] = {bb.x, bb.y, bb.z, bb.w};
#pragma unroll
  for (int i = 0; i < 4; i++) {
    int m = m0 + (ty << 2) + i;
    float4 o;
    o.x = fmaxf(acc[i][0] + bv[0], 0.f);
    o.y = fmaxf(acc[i][1] + bv[1], 0.f);
    o.z = fmaxf(acc[i][2] + bv[2], 0.f);
    o.w = fmaxf(acc[i][3] + bv[3], 0.f);
    *(float4*)&Y[(size_t)m * ldy + n0 + (tx << 2)] = o;
  }
}

// ---------------------------------------------------------------------------
// Fused weight prep: 8 transposes (W KxN fp32 -> Wt NxK bf16) in one dispatch.
// ---------------------------------------------------------------------------
struct TJobs {
  const float* W[8];
  __hip_bfloat16* Wt[8];
  int K[8], N[8], bx[8], off[8];
};

__global__ __launch_bounds__(256) void transpose_cast_all(TJobs jb)
{
  __shared__ float tile[32][33];
  int bid = blockIdx.x;
  int j = 0;
#pragma unroll
  for (int t = 1; t < 8; t++)
    if (bid >= jb.off[t]) j = t;
  int rel = bid - jb.off[j];
  int K = jb.K[j], N = jb.N[j];
  const float* W = jb.W[j];
  __hip_bfloat16* Wt = jb.Wt[j];
  int n0 = (rel % jb.bx[j]) << 5, k0 = (rel / jb.bx[j]) << 5;
  int c = threadIdx.x & 31, i0 = threadIdx.x >> 5;
#pragma unroll
  for (int p = 0; p < 4; p++) {
    int i = i0 + p * 8;
    tile[i][c] = W[(size_t)(k0 + i) * N + n0 + c];
  }
  __syncthreads();
#pragma unroll
  for (int p = 0; p < 4; p++) {
    int r = i0 + p * 8;
    Wt[(size_t)(n0 + r) * K + k0 + c] = (__hip_bfloat16)tile[c][r];
  }
}

// ---------------------------------------------------------------------------
// bf16 MFMA GEMM (unchanged).
// ---------------------------------------------------------------------------
template <bool OUT_BF16>
__global__ __launch_bounds__(256) void gemm_mfma(
    const __hip_bfloat16* __restrict__ A, int lda,
    const __hip_bfloat16* __restrict__ Wt, int ldw,
    const float* __restrict__ bias,
    void* __restrict__ Y, int ldy, int N, int K)
{
  __shared__ __align__(16) short As[128][40];
  __shared__ __align__(16) short Bs[128][40];
  int tid = threadIdx.x;
  int wave = tid >> 6, lane = tid & 63;
  int quad = lane >> 4, l16 = lane & 15;
  int m0 = blockIdx.y << 7, n0 = blockIdx.x << 7;
  int wm = (wave >> 1) << 6, wn = (wave & 1) << 6;
  f32x4 acc[4][4] = {};
  const short* Ag = (const short*)A;
  const short* Bg = (const short*)Wt;
  int srow = tid >> 2, sq = tid & 3;
  for (int k0 = 0; k0 < K; k0 += 32) {
#pragma unroll
    for (int h = 0; h < 2; h++) {
      int r = srow + (h << 6);
      uint4 va = *(const uint4*)&Ag[(size_t)(m0 + r) * lda + k0 + sq * 8];
      *(uint4*)&As[r][sq * 8] = va;
      uint4 vb = *(const uint4*)&Bg[(size_t)(n0 + r) * ldw + k0 + sq * 8];
      *(uint4*)&Bs[r][sq * 8] = vb;
    }
    __syncthreads();
    short8 a[4], b[4];
#pragma unroll
    for (int mi = 0; mi < 4; mi++)
      a[mi] = *(const short8*)&As[wm + mi * 16 + l16][quad * 8];
#pragma unroll
    for (int ni = 0; ni < 4; ni++)
      b[ni] = *(const short8*)&Bs[wn + ni * 16 + l16][quad * 8];
#pragma unroll
    for (int mi = 0; mi < 4; mi++)
#pragma unroll
      for (int ni = 0; ni < 4; ni++)
        acc[mi][ni] = __builtin_amdgcn_mfma_f32_16x16x32_bf16(
            a[mi], b[ni], acc[mi][ni], 0, 0, 0);
    __syncthreads();
  }
  float bn[4];
#pragma unroll
  for (int ni = 0; ni < 4; ni++) bn[ni] = bias[n0 + wn + ni * 16 + l16];
#pragma unroll
  for (int mi = 0; mi < 4; mi++)
#pragma unroll
    for (int ni = 0; ni < 4; ni++) {
      int n = n0 + wn + ni * 16 + l16;
#pragma unroll
      for (int r = 0; r < 4; r++) {
        int m = m0 + wm + mi * 16 + quad * 4 + r;
        float v = fmaxf(acc[mi][ni][r] + bn[ni], 0.f);
        if (OUT_BF16)
          ((__hip_bfloat16*)Y)[(size_t)m * ldy + n] = (__hip_bfloat16)v;
        else
          ((float*)Y)[(size_t)m * ldy + n] = v;
      }
    }
}

// ---------------------------------------------------------------------------
// fc2 + out head fused: out = sigmoid(relu(A@Wt^T + b) . wout + bout).
// ---------------------------------------------------------------------------
__global__ __launch_bounds__(256) void gemm_fc2_out(
    const __hip_bfloat16* __restrict__ A,      // 16384 x 256
    const __hip_bfloat16* __restrict__ Wt,     // 128 x 256
    const float* __restrict__ bias,            // 128
    const float* __restrict__ wout,            // 128
    const float* __restrict__ bout,            // 1
    float* __restrict__ out)                   // 16384
{
  __shared__ __align__(16) short As[128][40];
  __shared__ __align__(16) short Bs[128][40];
  __shared__ float red[128][2];
  const int N = 128, K = 256, lda = 256, ldw = 256;
  int tid = threadIdx.x;
  int wave = tid >> 6, lane = tid & 63;
  int quad = lane >> 4, l16 = lane & 15;
  int m0 = blockIdx.y << 7;
  int wm = (wave >> 1) << 6, wn = (wave & 1) << 6;
  f32x4 acc[4][4] = {};
  const short* Ag = (const short*)A;
  const short* Bg = (const short*)Wt;
  int srow = tid >> 2, sq = tid & 3;
  for (int k0 = 0; k0 < K; k0 += 32) {
#pragma unroll
    for (int h = 0; h < 2; h++) {
      int r = srow + (h << 6);
      uint4 va = *(const uint4*)&Ag[(size_t)(m0 + r) * lda + k0 + sq * 8];
      *(uint4*)&As[r][sq * 8] = va;
      uint4 vb = *(const uint4*)&Bg[(size_t)(r % N) * ldw + k0 + sq * 8];
      *(uint4*)&Bs[r][sq * 8] = vb;
    }
    __syncthreads();
    short8 a[4], b[4];
#pragma unroll
    for (int mi = 0; mi < 4; mi++)
      a[mi] = *(const short8*)&As[wm + mi * 16 + l16][quad * 8];
#pragma unroll
    for (int ni = 0; ni < 4; ni++)
      b[ni] = *(const short8*)&Bs[wn + ni * 16 + l16][quad * 8];
#pragma unroll
    for (int mi = 0; mi < 4; mi++)
#pragma unroll
      for (int ni = 0; ni < 4; ni++)
        acc[mi][ni] = __builtin_amdgcn_mfma_f32_16x16x32_bf16(
            a[mi], b[ni], acc[mi][ni], 0, 0, 0);
    __syncthreads();
  }
  float bn[4], wo[4];
#pragma unroll
  for (int ni = 0; ni < 4; ni++) {
    int n = wn + ni * 16 + l16;
    bn[ni] = bias[n];
    wo[ni] = wout[n];
  }
  float sacc[4][4];
#pragma unroll
  for (int mi = 0; mi < 4; mi++)
#pragma unroll
    for (int r = 0; r < 4; r++) {
      float s = 0.f;
#pragma unroll
      for (int ni = 0; ni < 4; ni++)
        s += fmaxf(acc[mi][ni][r] + bn[ni], 0.f) * wo[ni];
      sacc[mi][r] = s;
    }
#pragma unroll
  for (int off = 1; off < 16; off <<= 1)
#pragma unroll
    for (int mi = 0; mi < 4; mi++)
#pragma unroll
      for (int r = 0; r < 4; r++)
        sacc[mi][r] += __shfl_xor(sacc[mi][r], off);
  int wp = wave & 1;
  if (l16 == 0) {
#pragma unroll
    for (int mi = 0; mi < 4; mi++)
#pragma unroll
      for (int r = 0; r < 4; r++)
        red[wm + mi * 16 + quad * 4 + r][wp] = sacc[mi][r];
  }
  __syncthreads();
  if (tid < 128) {
    float s = red[tid][0] + red[tid][1] + bout[0];
    out[(size_t)(m0 + tid)] = 1.f / (1.f + expf(-s));
  }
}

// ---------------------------------------------------------------------------
// SA1 KNN v5: two-level threshold. 256 thread-mins -> 64 quad-mins via 4
// conflict-free vector ds_read_b64 (wave 0), rank within 64 qmins by a
// 64-iter broadcast loop (wave 0 only). T = 32nd-smallest qmin: the 32
// lowest-ranked qmins are 32 DISTINCT keys <= T (disjoint candidate sets)
// -> >=32 survivors -> superset of top-32. Exact O(s^2) rank-merge over
// survivors (expected ~44; buffer 2048 = always safe) -> selection
// bit-identical to v2/v3. [v4's 64-iter u64 __shfl rank = 128 bpermutes
// on the LDS pipe regressed 135 vs <116 — don't reintroduce.]
// ---------------------------------------------------------------------------
__global__ __launch_bounds__(256) void knn_mean_kernel(
    const float* __restrict__ X,
    const float* __restrict__ G1,
    float* __restrict__ X1,
    __hip_bfloat16* __restrict__ X1b)
{
  int q = blockIdx.x;
  int base = q & ~2047;
  int tid = threadIdx.x;
  __shared__ unsigned long long lmins[256];
  __shared__ unsigned long long qmins[64];
  __shared__ unsigned long long surv[2048];
  __shared__ unsigned long long thr;
  __shared__ int scnt;
  __shared__ int selidx[32];
  if (tid == 0) scnt = 0;
  float qx = X[(size_t)q * 2], qy = X[(size_t)q * 2 + 1];
  unsigned long long key[8];
#pragma unroll
  for (int u = 0; u < 8; u++) {
    int j = (u << 8) + tid;
    float dx = X[(size_t)(base + j) * 2] - qx;
    float dy = X[(size_t)(base + j) * 2 + 1] - qy;
    float d2 = dx * dx + dy * dy;
    key[u] = ((unsigned long long)__float_as_uint(d2) << 32) | (unsigned)j;
  }
  unsigned long long lm = key[0];
#pragma unroll
  for (int u = 1; u < 8; u++) lm = umin64(lm, key[u]);
  lmins[tid] = lm;
  __syncthreads();
  if (tid < 64) {
    unsigned long long qm = umin64(umin64(lmins[tid], lmins[tid + 64]),
                                   umin64(lmins[tid + 128], lmins[tid + 192]));
    qmins[tid] = qm;
    // same-wave write->read: in-order LDS per wave, no barrier needed
    int rank = 0;
    for (int i = 0; i < 64; i++) rank += (qmins[i] < qm);
    if (rank == 31) thr = qm;  // exactly one lane (unique keys)
  }
  __syncthreads();
  unsigned long long T = thr;
#pragma unroll
  for (int u = 0; u < 8; u++) {
    if (key[u] <= T) {
      int p = atomicAdd(&scnt, 1);
      surv[p] = key[u];
    }
  }
  __syncthreads();
  int s = scnt;  // >= 32 guaranteed
  for (int i = tid; i < s; i += 256) {
    unsigned long long c = surv[i];
    int r = 0;
    for (int j2 = 0; j2 < s; j2++) r += (surv[j2] < c);
    if (r < 32) selidx[r] = (int)(c & 0xffffffffULL);
  }
  __syncthreads();
  if (tid < 64) {
    float acc = 0.f;
#pragma unroll 4
    for (int sI = 0; sI < 32; sI++)
      acc += G1[(size_t)(base + selidx[sI]) * 64 + tid];
    float v = acc * (1.0f / 32.0f);
    X1[(size_t)q * 64 + tid] = v;
    X1b[(size_t)q * 64 + tid] = (__hip_bfloat16)v;
  }
}

// ---------------------------------------------------------------------------
// Ball-query pass 1 v4 (round-6 single-buffer version — the known 116 µs
// operating point; round-7 dbuf doubled LDS and cut residency 24->16
// waves/CU, a suspected regression. NO min-occupancy bound: 256,3 spilled
// the acc tile — 10x regression.)
// ---------------------------------------------------------------------------
template <int C>
__global__ __launch_bounds__(256) void ball_mask_sym(
    const float* __restrict__ F,
    unsigned long long* __restrict__ mask,
    float r2)
{
  __shared__ __align__(16) float As[16][132];
  __shared__ __align__(16) float Bs[16][132];
  __shared__ unsigned int tw[128][4];  // transposed bits: [c-local][q-word32]
  int tid = threadIdx.x;
  int tx = tid & 15, ty = tid >> 4;
  int p = blockIdx.x;
  int qt = 0;
  while (p >= 16 - qt) { p -= 16 - qt; qt++; }
  int ct = qt + p;
  int b0 = blockIdx.y << 11;
  int q0 = b0 + (qt << 7), c0 = b0 + (ct << 7);
  tw[tid >> 2][tid & 3] = 0;
  tw[(tid + 256) >> 2][tid & 3] = 0;
  f32x2 acc2[8][4] = {};
  for (int k0 = 0; k0 < C; k0 += 16) {
#pragma unroll
    for (int c = 0; c < 2; c++) {
      int idx = tid + (c << 8);
      int row = idx >> 2, qr = idx & 3;
      float4 va = *(const float4*)&F[(size_t)(q0 + row) * C + k0 + qr * 4];
      As[qr * 4 + 0][row] = va.x;
      As[qr * 4 + 1][row] = va.y;
      As[qr * 4 + 2][row] = va.z;
      As[qr * 4 + 3][row] = va.w;
      float4 vb = *(const float4*)&F[(size_t)(c0 + row) * C + k0 + qr * 4];
      Bs[qr * 4 + 0][row] = vb.x;
      Bs[qr * 4 + 1][row] = vb.y;
      Bs[qr * 4 + 2][row] = vb.z;
      Bs[qr * 4 + 3][row] = vb.w;
    }
    __syncthreads();
#pragma unroll
    for (int k = 0; k < 16; k++) {
      float av[8];
      f32x2 bv2[4];
      *(float4*)&av[0] = *(const float4*)&As[k][ty * 8];
      *(float4*)&av[4] = *(const float4*)&As[k][ty * 8 + 4];
      *(float4*)&bv2[0] = *(const float4*)&Bs[k][tx * 4];
      *(float4*)&bv2[2] = *(const float4*)&Bs[k][64 + tx * 4];
#pragma unroll
      for (int i = 0; i < 8; i++) {
        f32x2 a2 = {av[i], av[i]};
#pragma unroll
        for (int j2 = 0; j2 < 4; j2++) {
          f32x2 d = a2 - bv2[j2];
          acc2[i][j2] += d * d;
        }
      }
    }
    __syncthreads();
  }
  int w0 = ct << 1;
  unsigned int bytes[8] = {0, 0, 0, 0, 0, 0, 0, 0};
#pragma unroll
  for (int i = 0; i < 8; i++) {
    unsigned long long wlo = 0, whi = 0;
#pragma unroll
    for (int j = 0; j < 4; j++) {
      float dlo = acc2[i][j >> 1][j & 1];
      float dhi = acc2[i][2 + (j >> 1)][j & 1];
      if (dlo <= r2) { wlo |= 1ULL << (tx * 4 + j); bytes[j] |= 1u << i; }
      if (dhi <= r2) { whi |= 1ULL << (tx * 4 + j); bytes[4 + j] |= 1u << i; }
    }
#pragma unroll
    for (int s = 1; s <= 8; s <<= 1) {
      wlo |= __shfl_xor(wlo, s);
      whi |= __shfl_xor(whi, s);
    }
    if (tx == 0) {
      int q = q0 + ty * 8 + i;
      mask[(size_t)q * 32 + w0] = wlo;
      mask[(size_t)q * 32 + w0 + 1] = whi;
    }
  }
  if (qt != ct) {
    int sh = (ty & 3) * 8, wq = ty >> 2;
#pragma unroll
    for (int j2 = 0; j2 < 8; j2++) {
      int cl = ((j2 >> 2) << 6) + tx * 4 + (j2 & 3);
      atomicOr(&tw[cl][wq], bytes[j2] << sh);
    }
    __syncthreads();
    int row = tid >> 1, word = tid & 1;
    unsigned long long v = (unsigned long long)tw[row][word * 2] |
                           ((unsigned long long)tw[row][word * 2 + 1] << 32);
    mask[(size_t)(c0 + row) * 32 + (qt << 1) + word] = v;
  }
}

// ---------------------------------------------------------------------------
// Ball-query pass 2 (templated input dtype; fp32 accumulate).
// ---------------------------------------------------------------------------
template <typename TIn>
__global__ void ball_gather_kernel(
    const unsigned long long* __restrict__ mask,
    const TIn* __restrict__ H, int CH,
    float* __restrict__ Yf, __hip_bfloat16* __restrict__ Yb,
    int ldy, int S)
{
  int q = blockIdx.x;
  int base = q & ~2047;
  int tid = threadIdx.x;
  __shared__ int idxl[64];
  __shared__ float wtab[64];
  __shared__ int scount;
  if (tid < 32) {
    unsigned long long w = mask[(size_t)q * 32 + tid];
    int cnt = __popcll(w);
    int inc = cnt;
#pragma unroll
    for (int off = 1; off < 32; off <<= 1) {
      int o = __shfl_up(inc, off);
      if (tid >= off) inc += o;
    }
    if (tid == 31) scount = inc;
    int p = inc - cnt;
    while (w && p < 64) {
      int j = (tid << 6) + __builtin_ctzll(w);
      w &= w - 1;
      idxl[p++] = j;
    }
  }
  __syncthreads();
  int c = scount;
  if (tid < 64) {
    int p = tid;
    int cnt = (p < c && p < S) ? ((S - 1 - p) / c + 1) : 0;
    wtab[p] = (float)cnt / (float)S;
  }
  __syncthreads();
  float acc = 0.f;
  int lim = c < S ? c : S;
#pragma unroll 4
  for (int s = 0; s < lim; s++)
    acc += wtab[s] * (float)H[(size_t)(base + idxl[s]) * CH + tid];
  if (Yf) Yf[(size_t)q * ldy + tid] = acc;
  if (Yb) Yb[(size_t)q * ldy + tid] = (__hip_bfloat16)acc;
}

// ---------------------------------------------------------------------------
extern "C" void kernel_launch(void* const* d_in, const int* in_sizes, int n_in,
                              void* d_out, int out_size, void* d_ws,
                              size_t ws_size, hipStream_t stream)
{
  const float* x      = (const float*)d_in[0];
  const float* sa1_w0 = (const float*)d_in[1];
  const float* sa1_b0 = (const float*)d_in[2];
  const float* sa1_w1 = (const float*)d_in[3];
  const float* sa1_b1 = (const float*)d_in[4];
  const float* sa2_w0 = (const float*)d_in[5];
  const float* sa2_b0 = (const float*)d_in[6];
  const float* sa2_w1 = (const float*)d_in[7];
  const float* sa2_b1 = (const float*)d_in[8];
  const float* sa3_w0 = (const float*)d_in[9];
  const float* sa3_b0 = (const float*)d_in[10];
  const float* sa3_w1 = (const float*)d_in[11];
  const float* sa3_b1 = (const float*)d_in[12];
  const float* fp1_w0 = (const float*)d_in[13];
  const float* fp1_b0 = (const float*)d_in[14];
  const float* fp1_w1 = (const float*)d_in[15];
  const float* fp1_b1 = (const float*)d_in[16];
  const float* fp2_w0 = (const float*)d_in[17];
  const float* fp2_b0 = (const float*)d_in[18];
  const float* fp2_w1 = (const float*)d_in[19];
  const float* fp2_b1 = (const float*)d_in[20];
  const float* fc1_w  = (const float*)d_in[21];
  const float* fc1_b  = (const float*)d_in[22];
  const float* fc2_w  = (const float*)d_in[23];
  const float* fc2_b  = (const float*)d_in[24];
  const float* out_w  = (const float*)d_in[25];
  const float* out_b  = (const float*)d_in[26];
  float* out = (float*)d_out;

  const size_t M = M_ROWS;
  float* ws = (float*)d_ws;
  float* T   = ws;             // M*256
  float* G1  = ws + M * 256;   // M*64
  float* X1  = ws + M * 320;   // M*64
  float* X2  = ws + M * 384;   // M*128
  float* H2  = ws + M * 512;   // M*128 (sa2 out fp32)
  __hip_bfloat16* H3b16 = (__hip_bfloat16*)(ws + M * 640);  // M*256 bf16 (sa3 out)
  unsigned long long* MASK = (unsigned long long*)(ws + M * 896);  // M*32 u64
  __hip_bfloat16* X1b = (__hip_bfloat16*)(ws + M * 960);   // M*64
  __hip_bfloat16* X2b = (__hip_bfloat16*)(ws + M * 992);   // M*128
  __hip_bfloat16* TB  = (__hip_bfloat16*)(ws + M * 1056);  // M*512
  __hip_bfloat16* G   = (__hip_bfloat16*)(ws + M * 1312);  // M*1024
  __hip_bfloat16* H3b = (__hip_bfloat16*)(ws + M * 1824);  // M*256 (fc1 out)
  __hip_bfloat16* WB  = (__hip_bfloat16*)(ws + M * 1952);
  if (ws_size < (size_t)M * 1984 * sizeof(float)) return;
  __hip_bfloat16* w_sa3_0 = WB;               // 256x128
  __hip_bfloat16* w_sa3_1 = w_sa3_0 + 32768;  // 256x256
  __hip_bfloat16* w_fp1_0 = w_sa3_1 + 65536;  // 512x128
  __hip_bfloat16* w_fp1_1 = w_fp1_0 + 65536;  // 512x512
  __hip_bfloat16* w_fp2_0 = w_fp1_1 + 262144; // 256x64
  __hip_bfloat16* w_fp2_1 = w_fp2_0 + 16384;  // 256x256
  __hip_bfloat16* w_fc1   = w_fp2_1 + 65536;  // 256x1024
  __hip_bfloat16* w_fc2   = w_fc1 + 262144;   // 128x256

  dim3 blk(256);
  TJobs jb;
  const float* srcs[8] = {sa3_w0, sa3_w1, fp1_w0, fp1_w1, fp2_w0, fp2_w1, fc1_w, fc2_w};
  __hip_bfloat16* dsts[8] = {w_sa3_0, w_sa3_1, w_fp1_0, w_fp1_1, w_fp2_0, w_fp2_1, w_fc1, w_fc2};
  int Ks[8] = {128, 256, 128, 512, 64, 256, 1024, 256};
  int Ns[8] = {256, 256, 512, 512, 256, 256, 256, 128};
  int off = 0;
  for (int i = 0; i < 8; i++) {
    jb.W[i] = srcs[i]; jb.Wt[i] = dsts[i];
    jb.K[i] = Ks[i]; jb.N[i] = Ns[i];
    jb.bx[i] = Ns[i] >> 5;
    jb.off[i] = off;
    off += (Ns[i] >> 5) * (Ks[i] >> 5);
  }
  transpose_cast_all<<<off, blk, 0, stream>>>(jb);

  // SA1 (fp32 exact).
  gemm_bias_relu<<<dim3(1, 256), blk, 0, stream>>>(x, 2, sa1_w0, sa1_b0, T, 64, 64, 2);
  gemm_bias_relu<<<dim3(1, 256), blk, 0, stream>>>(T, 64, sa1_w1, sa1_b1, G1, 64, 64, 64);
  knn_mean_kernel<<<16384, 256, 0, stream>>>(x, G1, X1, X1b);
  // SA2 (fp32 exact).
  gemm_bias_relu<<<dim3(2, 256), blk, 0, stream>>>(X1, 64, sa2_w0, sa2_b0, T, 128, 128, 64);
  gemm_bias_relu<<<dim3(2, 256), blk, 0, stream>>>(T, 128, sa2_w1, sa2_b1, H2, 128, 128, 128);
  ball_mask_sym<64><<<dim3(136, 8), blk, 0, stream>>>(X1, MASK, 0.2f * 0.2f);
  ball_gather_kernel<float><<<16384, 128, 0, stream>>>(MASK, H2, 128, X2, X2b, 128, 32);
  // SA3 MLP (bf16 MFMA; output stored bf16 — only feeds bf16 G columns).
  gemm_mfma<true><<<dim3(2, 128), blk, 0, stream>>>(X2b, 128, w_sa3_0, 128, sa3_b0, TB, 256, 256, 128);
  gemm_mfma<true><<<dim3(2, 128), blk, 0, stream>>>(TB, 256, w_sa3_1, 256, sa3_b1, H3b16, 256, 256, 256);
  ball_mask_sym<128><<<dim3(136, 8), blk, 0, stream>>>(X2, MASK, 0.4f * 0.4f);
  ball_gather_kernel<__hip_bfloat16><<<16384, 256, 0, stream>>>(MASK, H3b16, 256, nullptr, G + 768, 1024, 64);
  // FP1 (bf16).
  gemm_mfma<true><<<dim3(4, 128), blk, 0, stream>>>(X2b, 128, w_fp1_0, 128, fp1_b0, TB, 512, 512, 128);
  gemm_mfma<true><<<dim3(4, 128), blk, 0, stream>>>(TB, 512, w_fp1_1, 512, fp1_b1, G + 256, 1024, 512, 512);
  // FP2 (bf16).
  gemm_mfma<true><<<dim3(2, 128), blk, 0, stream>>>(X1b, 64, w_fp2_0, 64, fp2_b0, TB, 256, 256, 64);
  gemm_mfma<true><<<dim3(2, 128), blk, 0, stream>>>(TB, 256, w_fp2_1, 256, fp2_b1, G, 1024, 256, 256);
  // Head: fc1 (bf16), then fc2+out fused.
  gemm_mfma<true><<<dim3(2, 128), blk, 0, stream>>>(G, 1024, w_fc1, 1024, fc1_b, H3b, 256, 256, 1024);
  gemm_fc2_out<<<dim3(1, 128), blk, 0, stream>>>(H3b, w_fc2, fc2_b, out_w, out_b, out);
}

// Round 10
// 491.397 us; speedup vs baseline: 1.1777x; 1.0587x over previous
//
#include <hip/hip_runtime.h>
#include <hip/hip_bf16.h>
#include <cstdint>

#define M_ROWS 16384

typedef __attribute__((ext_vector_type(8))) short short8;
typedef __attribute__((ext_vector_type(4))) float f32x4;
typedef __attribute__((ext_vector_type(2))) float f32x2;

__device__ __forceinline__ unsigned long long umin64(unsigned long long a,
                                                     unsigned long long b) {
  return a < b ? a : b;
}

// ---------------------------------------------------------------------------
// fp32 GEMM (SA1/SA2 — feeds masks, bit-identical path).
// ---------------------------------------------------------------------------
__global__ __launch_bounds__(256) void gemm_bias_relu(
    const float* __restrict__ X, int ldx,
    const float* __restrict__ W,
    const float* __restrict__ bias,
    float* __restrict__ Y, int ldy,
    int N, int K)
{
  __shared__ __align__(16) float As[16][68];
  __shared__ __align__(16) float Bs[16][68];
  int tid = threadIdx.x;
  int tx = tid & 15, ty = tid >> 4;
  int m0 = blockIdx.y << 6, n0 = blockIdx.x << 6;
  float acc[4][4] = {};
  for (int k0 = 0; k0 < K; k0 += 16) {
#pragma unroll
    for (int i = 0; i < 4; i++) {
      int idx = tid + (i << 8);
      int m = idx >> 4, k = idx & 15;
      As[k][m] = (k0 + k < K) ? X[(size_t)(m0 + m) * ldx + k0 + k] : 0.f;
    }
#pragma unroll
    for (int i = 0; i < 4; i++) {
      int idx = tid + (i << 8);
      int n = idx & 63, k = idx >> 6;
      Bs[k][n] = (k0 + k < K) ? W[(size_t)(k0 + k) * N + n0 + n] : 0.f;
    }
    __syncthreads();
#pragma unroll
    for (int k = 0; k < 16; k++) {
      float4 a4 = *(const float4*)&As[k][ty << 2];
      float4 b4 = *(const float4*)&Bs[k][tx << 2];
      float av[4] = {a4.x, a4.y, a4.z, a4.w};
      float bv[4] = {b4.x, b4.y, b4.z, b4.w};
#pragma unroll
      for (int i = 0; i < 4; i++)
#pragma unroll
        for (int j = 0; j < 4; j++)
          acc[i][j] += av[i] * bv[j];
    }
    __syncthreads();
  }
  float4 bb = *(const float4*)&bias[n0 + (tx << 2)];
  float bv[4] = {bb.x, bb.y, bb.z, bb.w};
#pragma unroll
  for (int i = 0; i < 4; i++) {
    int m = m0 + (ty << 2) + i;
    float4 o;
    o.x = fmaxf(acc[i][0] + bv[0], 0.f);
    o.y = fmaxf(acc[i][1] + bv[1], 0.f);
    o.z = fmaxf(acc[i][2] + bv[2], 0.f);
    o.w = fmaxf(acc[i][3] + bv[3], 0.f);
    *(float4*)&Y[(size_t)m * ldy + n0 + (tx << 2)] = o;
  }
}

// ---------------------------------------------------------------------------
// Fused weight prep: 8 transposes (W KxN fp32 -> Wt NxK bf16) in one dispatch.
// ---------------------------------------------------------------------------
struct TJobs {
  const float* W[8];
  __hip_bfloat16* Wt[8];
  int K[8], N[8], bx[8], off[8];
};

__global__ __launch_bounds__(256) void transpose_cast_all(TJobs jb)
{
  __shared__ float tile[32][33];
  int bid = blockIdx.x;
  int j = 0;
#pragma unroll
  for (int t = 1; t < 8; t++)
    if (bid >= jb.off[t]) j = t;
  int rel = bid - jb.off[j];
  int K = jb.K[j], N = jb.N[j];
  const float* W = jb.W[j];
  __hip_bfloat16* Wt = jb.Wt[j];
  int n0 = (rel % jb.bx[j]) << 5, k0 = (rel / jb.bx[j]) << 5;
  int c = threadIdx.x & 31, i0 = threadIdx.x >> 5;
#pragma unroll
  for (int p = 0; p < 4; p++) {
    int i = i0 + p * 8;
    tile[i][c] = W[(size_t)(k0 + i) * N + n0 + c];
  }
  __syncthreads();
#pragma unroll
  for (int p = 0; p < 4; p++) {
    int r = i0 + p * 8;
    Wt[(size_t)(n0 + r) * K + k0 + c] = (__hip_bfloat16)tile[c][r];
  }
}

// ---------------------------------------------------------------------------
// bf16 MFMA GEMM (single-job; used for fc1).
// ---------------------------------------------------------------------------
template <bool OUT_BF16>
__global__ __launch_bounds__(256) void gemm_mfma(
    const __hip_bfloat16* __restrict__ A, int lda,
    const __hip_bfloat16* __restrict__ Wt, int ldw,
    const float* __restrict__ bias,
    void* __restrict__ Y, int ldy, int N, int K)
{
  __shared__ __align__(16) short As[128][40];
  __shared__ __align__(16) short Bs[128][40];
  int tid = threadIdx.x;
  int wave = tid >> 6, lane = tid & 63;
  int quad = lane >> 4, l16 = lane & 15;
  int m0 = blockIdx.y << 7, n0 = blockIdx.x << 7;
  int wm = (wave >> 1) << 6, wn = (wave & 1) << 6;
  f32x4 acc[4][4] = {};
  const short* Ag = (const short*)A;
  const short* Bg = (const short*)Wt;
  int srow = tid >> 2, sq = tid & 3;
  for (int k0 = 0; k0 < K; k0 += 32) {
#pragma unroll
    for (int h = 0; h < 2; h++) {
      int r = srow + (h << 6);
      uint4 va = *(const uint4*)&Ag[(size_t)(m0 + r) * lda + k0 + sq * 8];
      *(uint4*)&As[r][sq * 8] = va;
      uint4 vb = *(const uint4*)&Bg[(size_t)(n0 + r) * ldw + k0 + sq * 8];
      *(uint4*)&Bs[r][sq * 8] = vb;
    }
    __syncthreads();
    short8 a[4], b[4];
#pragma unroll
    for (int mi = 0; mi < 4; mi++)
      a[mi] = *(const short8*)&As[wm + mi * 16 + l16][quad * 8];
#pragma unroll
    for (int ni = 0; ni < 4; ni++)
      b[ni] = *(const short8*)&Bs[wn + ni * 16 + l16][quad * 8];
#pragma unroll
    for (int mi = 0; mi < 4; mi++)
#pragma unroll
      for (int ni = 0; ni < 4; ni++)
        acc[mi][ni] = __builtin_amdgcn_mfma_f32_16x16x32_bf16(
            a[mi], b[ni], acc[mi][ni], 0, 0, 0);
    __syncthreads();
  }
  float bn[4];
#pragma unroll
  for (int ni = 0; ni < 4; ni++) bn[ni] = bias[n0 + wn + ni * 16 + l16];
#pragma unroll
  for (int mi = 0; mi < 4; mi++)
#pragma unroll
    for (int ni = 0; ni < 4; ni++) {
      int n = n0 + wn + ni * 16 + l16;
#pragma unroll
      for (int r = 0; r < 4; r++) {
        int m = m0 + wm + mi * 16 + quad * 4 + r;
        float v = fmaxf(acc[mi][ni][r] + bn[ni], 0.f);
        if (OUT_BF16)
          ((__hip_bfloat16*)Y)[(size_t)m * ldy + n] = (__hip_bfloat16)v;
        else
          ((float*)Y)[(size_t)m * ldy + n] = v;
      }
    }
}

// ---------------------------------------------------------------------------
// Multi-job bf16 MFMA GEMM: 3 independent GEMMs in ONE dispatch (job picked
// by blockIdx range). Same math as gemm_mfma -> bit-identical outputs;
// merging fixes the 1-block/CU fill of the small dispatches.
// ---------------------------------------------------------------------------
struct GJobs {
  const short* A[3];
  const short* W[3];
  const float* bias[3];
  __hip_bfloat16* Y[3];
  int lda[3], ldw[3], ldy[3], N[3], K[3], xt[3], off[3];
};

__global__ __launch_bounds__(256) void gemm_mfma_multi(GJobs g)
{
  __shared__ __align__(16) short As[128][40];
  __shared__ __align__(16) short Bs[128][40];
  int bid = blockIdx.x;
  int j = 0;
#pragma unroll
  for (int t = 1; t < 3; t++)
    if (bid >= g.off[t]) j = t;
  int rel = bid - g.off[j];
  int xt = g.xt[j];
  int m0 = (rel / xt) << 7, n0 = (rel % xt) << 7;
  int lda = g.lda[j], ldw = g.ldw[j], ldy = g.ldy[j], K = g.K[j];
  const short* Ag = g.A[j];
  const short* Bg = g.W[j];
  const float* bias = g.bias[j];
  __hip_bfloat16* Y = g.Y[j];

  int tid = threadIdx.x;
  int wave = tid >> 6, lane = tid & 63;
  int quad = lane >> 4, l16 = lane & 15;
  int wm = (wave >> 1) << 6, wn = (wave & 1) << 6;
  f32x4 acc[4][4] = {};
  int srow = tid >> 2, sq = tid & 3;
  for (int k0 = 0; k0 < K; k0 += 32) {
#pragma unroll
    for (int h = 0; h < 2; h++) {
      int r = srow + (h << 6);
      uint4 va = *(const uint4*)&Ag[(size_t)(m0 + r) * lda + k0 + sq * 8];
      *(uint4*)&As[r][sq * 8] = va;
      uint4 vb = *(const uint4*)&Bg[(size_t)(n0 + r) * ldw + k0 + sq * 8];
      *(uint4*)&Bs[r][sq * 8] = vb;
    }
    __syncthreads();
    short8 a[4], b[4];
#pragma unroll
    for (int mi = 0; mi < 4; mi++)
      a[mi] = *(const short8*)&As[wm + mi * 16 + l16][quad * 8];
#pragma unroll
    for (int ni = 0; ni < 4; ni++)
      b[ni] = *(const short8*)&Bs[wn + ni * 16 + l16][quad * 8];
#pragma unroll
    for (int mi = 0; mi < 4; mi++)
#pragma unroll
      for (int ni = 0; ni < 4; ni++)
        acc[mi][ni] = __builtin_amdgcn_mfma_f32_16x16x32_bf16(
            a[mi], b[ni], acc[mi][ni], 0, 0, 0);
    __syncthreads();
  }
  float bn[4];
#pragma unroll
  for (int ni = 0; ni < 4; ni++) bn[ni] = bias[n0 + wn + ni * 16 + l16];
#pragma unroll
  for (int mi = 0; mi < 4; mi++)
#pragma unroll
    for (int ni = 0; ni < 4; ni++) {
      int n = n0 + wn + ni * 16 + l16;
#pragma unroll
      for (int r = 0; r < 4; r++) {
        int m = m0 + wm + mi * 16 + quad * 4 + r;
        float v = fmaxf(acc[mi][ni][r] + bn[ni], 0.f);
        Y[(size_t)m * ldy + n] = (__hip_bfloat16)v;
      }
    }
}

// ---------------------------------------------------------------------------
// fc2 + out head fused: out = sigmoid(relu(A@Wt^T + b) . wout + bout).
// ---------------------------------------------------------------------------
__global__ __launch_bounds__(256) void gemm_fc2_out(
    const __hip_bfloat16* __restrict__ A,      // 16384 x 256
    const __hip_bfloat16* __restrict__ Wt,     // 128 x 256
    const float* __restrict__ bias,            // 128
    const float* __restrict__ wout,            // 128
    const float* __restrict__ bout,            // 1
    float* __restrict__ out)                   // 16384
{
  __shared__ __align__(16) short As[128][40];
  __shared__ __align__(16) short Bs[128][40];
  __shared__ float red[128][2];
  const int N = 128, K = 256, lda = 256, ldw = 256;
  int tid = threadIdx.x;
  int wave = tid >> 6, lane = tid & 63;
  int quad = lane >> 4, l16 = lane & 15;
  int m0 = blockIdx.y << 7;
  int wm = (wave >> 1) << 6, wn = (wave & 1) << 6;
  f32x4 acc[4][4] = {};
  const short* Ag = (const short*)A;
  const short* Bg = (const short*)Wt;
  int srow = tid >> 2, sq = tid & 3;
  for (int k0 = 0; k0 < K; k0 += 32) {
#pragma unroll
    for (int h = 0; h < 2; h++) {
      int r = srow + (h << 6);
      uint4 va = *(const uint4*)&Ag[(size_t)(m0 + r) * lda + k0 + sq * 8];
      *(uint4*)&As[r][sq * 8] = va;
      uint4 vb = *(const uint4*)&Bg[(size_t)(r % N) * ldw + k0 + sq * 8];
      *(uint4*)&Bs[r][sq * 8] = vb;
    }
    __syncthreads();
    short8 a[4], b[4];
#pragma unroll
    for (int mi = 0; mi < 4; mi++)
      a[mi] = *(const short8*)&As[wm + mi * 16 + l16][quad * 8];
#pragma unroll
    for (int ni = 0; ni < 4; ni++)
      b[ni] = *(const short8*)&Bs[wn + ni * 16 + l16][quad * 8];
#pragma unroll
    for (int mi = 0; mi < 4; mi++)
#pragma unroll
      for (int ni = 0; ni < 4; ni++)
        acc[mi][ni] = __builtin_amdgcn_mfma_f32_16x16x32_bf16(
            a[mi], b[ni], acc[mi][ni], 0, 0, 0);
    __syncthreads();
  }
  float bn[4], wo[4];
#pragma unroll
  for (int ni = 0; ni < 4; ni++) {
    int n = wn + ni * 16 + l16;
    bn[ni] = bias[n];
    wo[ni] = wout[n];
  }
  float sacc[4][4];
#pragma unroll
  for (int mi = 0; mi < 4; mi++)
#pragma unroll
    for (int r = 0; r < 4; r++) {
      float s = 0.f;
#pragma unroll
      for (int ni = 0; ni < 4; ni++)
        s += fmaxf(acc[mi][ni][r] + bn[ni], 0.f) * wo[ni];
      sacc[mi][r] = s;
    }
#pragma unroll
  for (int off = 1; off < 16; off <<= 1)
#pragma unroll
    for (int mi = 0; mi < 4; mi++)
#pragma unroll
      for (int r = 0; r < 4; r++)
        sacc[mi][r] += __shfl_xor(sacc[mi][r], off);
  int wp = wave & 1;
  if (l16 == 0) {
#pragma unroll
    for (int mi = 0; mi < 4; mi++)
#pragma unroll
      for (int r = 0; r < 4; r++)
        red[wm + mi * 16 + quad * 4 + r][wp] = sacc[mi][r];
  }
  __syncthreads();
  if (tid < 128) {
    float s = red[tid][0] + red[tid][1] + bout[0];
    out[(size_t)(m0 + tid)] = 1.f / (1.f + expf(-s));
  }
}

// ---------------------------------------------------------------------------
// SA1 KNN v5 (round-8 version — two-level threshold, passing).
// ---------------------------------------------------------------------------
__global__ __launch_bounds__(256) void knn_mean_kernel(
    const float* __restrict__ X,
    const float* __restrict__ G1,
    float* __restrict__ X1,
    __hip_bfloat16* __restrict__ X1b)
{
  int q = blockIdx.x;
  int base = q & ~2047;
  int tid = threadIdx.x;
  __shared__ unsigned long long lmins[256];
  __shared__ unsigned long long qmins[64];
  __shared__ unsigned long long surv[2048];
  __shared__ unsigned long long thr;
  __shared__ int scnt;
  __shared__ int selidx[32];
  if (tid == 0) scnt = 0;
  float qx = X[(size_t)q * 2], qy = X[(size_t)q * 2 + 1];
  unsigned long long key[8];
#pragma unroll
  for (int u = 0; u < 8; u++) {
    int j = (u << 8) + tid;
    float dx = X[(size_t)(base + j) * 2] - qx;
    float dy = X[(size_t)(base + j) * 2 + 1] - qy;
    float d2 = dx * dx + dy * dy;
    key[u] = ((unsigned long long)__float_as_uint(d2) << 32) | (unsigned)j;
  }
  unsigned long long lm = key[0];
#pragma unroll
  for (int u = 1; u < 8; u++) lm = umin64(lm, key[u]);
  lmins[tid] = lm;
  __syncthreads();
  if (tid < 64) {
    unsigned long long qm = umin64(umin64(lmins[tid], lmins[tid + 64]),
                                   umin64(lmins[tid + 128], lmins[tid + 192]));
    qmins[tid] = qm;
    int rank = 0;
    for (int i = 0; i < 64; i++) rank += (qmins[i] < qm);
    if (rank == 31) thr = qm;
  }
  __syncthreads();
  unsigned long long T = thr;
#pragma unroll
  for (int u = 0; u < 8; u++) {
    if (key[u] <= T) {
      int p = atomicAdd(&scnt, 1);
      surv[p] = key[u];
    }
  }
  __syncthreads();
  int s = scnt;
  for (int i = tid; i < s; i += 256) {
    unsigned long long c = surv[i];
    int r = 0;
    for (int j2 = 0; j2 < s; j2++) r += (surv[j2] < c);
    if (r < 32) selidx[r] = (int)(c & 0xffffffffULL);
  }
  __syncthreads();
  if (tid < 64) {
    float acc = 0.f;
#pragma unroll 4
    for (int sI = 0; sI < 32; sI++)
      acc += G1[(size_t)(base + selidx[sI]) * 64 + tid];
    float v = acc * (1.0f / 32.0f);
    X1[(size_t)q * 64 + tid] = v;
    X1b[(size_t)q * 64 + tid] = (__hip_bfloat16)v;
  }
}

// ---------------------------------------------------------------------------
// Ball-query pass 1 (round-8 version — symmetric, single-buffer, packed
// inner, no min-occupancy bound). Near its VALU-issue floor.
// ---------------------------------------------------------------------------
template <int C>
__global__ __launch_bounds__(256) void ball_mask_sym(
    const float* __restrict__ F,
    unsigned long long* __restrict__ mask,
    float r2)
{
  __shared__ __align__(16) float As[16][132];
  __shared__ __align__(16) float Bs[16][132];
  __shared__ unsigned int tw[128][4];
  int tid = threadIdx.x;
  int tx = tid & 15, ty = tid >> 4;
  int p = blockIdx.x;
  int qt = 0;
  while (p >= 16 - qt) { p -= 16 - qt; qt++; }
  int ct = qt + p;
  int b0 = blockIdx.y << 11;
  int q0 = b0 + (qt << 7), c0 = b0 + (ct << 7);
  tw[tid >> 2][tid & 3] = 0;
  tw[(tid + 256) >> 2][tid & 3] = 0;
  f32x2 acc2[8][4] = {};
  for (int k0 = 0; k0 < C; k0 += 16) {
#pragma unroll
    for (int c = 0; c < 2; c++) {
      int idx = tid + (c << 8);
      int row = idx >> 2, qr = idx & 3;
      float4 va = *(const float4*)&F[(size_t)(q0 + row) * C + k0 + qr * 4];
      As[qr * 4 + 0][row] = va.x;
      As[qr * 4 + 1][row] = va.y;
      As[qr * 4 + 2][row] = va.z;
      As[qr * 4 + 3][row] = va.w;
      float4 vb = *(const float4*)&F[(size_t)(c0 + row) * C + k0 + qr * 4];
      Bs[qr * 4 + 0][row] = vb.x;
      Bs[qr * 4 + 1][row] = vb.y;
      Bs[qr * 4 + 2][row] = vb.z;
      Bs[qr * 4 + 3][row] = vb.w;
    }
    __syncthreads();
#pragma unroll
    for (int k = 0; k < 16; k++) {
      float av[8];
      f32x2 bv2[4];
      *(float4*)&av[0] = *(const float4*)&As[k][ty * 8];
      *(float4*)&av[4] = *(const float4*)&As[k][ty * 8 + 4];
      *(float4*)&bv2[0] = *(const float4*)&Bs[k][tx * 4];
      *(float4*)&bv2[2] = *(const float4*)&Bs[k][64 + tx * 4];
#pragma unroll
      for (int i = 0; i < 8; i++) {
        f32x2 a2 = {av[i], av[i]};
#pragma unroll
        for (int j2 = 0; j2 < 4; j2++) {
          f32x2 d = a2 - bv2[j2];
          acc2[i][j2] += d * d;
        }
      }
    }
    __syncthreads();
  }
  int w0 = ct << 1;
  unsigned int bytes[8] = {0, 0, 0, 0, 0, 0, 0, 0};
#pragma unroll
  for (int i = 0; i < 8; i++) {
    unsigned long long wlo = 0, whi = 0;
#pragma unroll
    for (int j = 0; j < 4; j++) {
      float dlo = acc2[i][j >> 1][j & 1];
      float dhi = acc2[i][2 + (j >> 1)][j & 1];
      if (dlo <= r2) { wlo |= 1ULL << (tx * 4 + j); bytes[j] |= 1u << i; }
      if (dhi <= r2) { whi |= 1ULL << (tx * 4 + j); bytes[4 + j] |= 1u << i; }
    }
#pragma unroll
    for (int s = 1; s <= 8; s <<= 1) {
      wlo |= __shfl_xor(wlo, s);
      whi |= __shfl_xor(whi, s);
    }
    if (tx == 0) {
      int q = q0 + ty * 8 + i;
      mask[(size_t)q * 32 + w0] = wlo;
      mask[(size_t)q * 32 + w0 + 1] = whi;
    }
  }
  if (qt != ct) {
    int sh = (ty & 3) * 8, wq = ty >> 2;
#pragma unroll
    for (int j2 = 0; j2 < 8; j2++) {
      int cl = ((j2 >> 2) << 6) + tx * 4 + (j2 & 3);
      atomicOr(&tw[cl][wq], bytes[j2] << sh);
    }
    __syncthreads();
    int row = tid >> 1, word = tid & 1;
    unsigned long long v = (unsigned long long)tw[row][word * 2] |
                           ((unsigned long long)tw[row][word * 2 + 1] << 32);
    mask[(size_t)(c0 + row) * 32 + (qt << 1) + word] = v;
  }
}

// ---------------------------------------------------------------------------
// Ball-query pass 2 (templated input dtype; fp32 accumulate).
// ---------------------------------------------------------------------------
template <typename TIn>
__global__ void ball_gather_kernel(
    const unsigned long long* __restrict__ mask,
    const TIn* __restrict__ H, int CH,
    float* __restrict__ Yf, __hip_bfloat16* __restrict__ Yb,
    int ldy, int S)
{
  int q = blockIdx.x;
  int base = q & ~2047;
  int tid = threadIdx.x;
  __shared__ int idxl[64];
  __shared__ float wtab[64];
  __shared__ int scount;
  if (tid < 32) {
    unsigned long long w = mask[(size_t)q * 32 + tid];
    int cnt = __popcll(w);
    int inc = cnt;
#pragma unroll
    for (int off = 1; off < 32; off <<= 1) {
      int o = __shfl_up(inc, off);
      if (tid >= off) inc += o;
    }
    if (tid == 31) scount = inc;
    int p = inc - cnt;
    while (w && p < 64) {
      int j = (tid << 6) + __builtin_ctzll(w);
      w &= w - 1;
      idxl[p++] = j;
    }
  }
  __syncthreads();
  int c = scount;
  if (tid < 64) {
    int p = tid;
    int cnt = (p < c && p < S) ? ((S - 1 - p) / c + 1) : 0;
    wtab[p] = (float)cnt / (float)S;
  }
  __syncthreads();
  float acc = 0.f;
  int lim = c < S ? c : S;
#pragma unroll 4
  for (int s = 0; s < lim; s++)
    acc += wtab[s] * (float)H[(size_t)(base + idxl[s]) * CH + tid];
  if (Yf) Yf[(size_t)q * ldy + tid] = acc;
  if (Yb) Yb[(size_t)q * ldy + tid] = (__hip_bfloat16)acc;
}

// ---------------------------------------------------------------------------
extern "C" void kernel_launch(void* const* d_in, const int* in_sizes, int n_in,
                              void* d_out, int out_size, void* d_ws,
                              size_t ws_size, hipStream_t stream)
{
  const float* x      = (const float*)d_in[0];
  const float* sa1_w0 = (const float*)d_in[1];
  const float* sa1_b0 = (const float*)d_in[2];
  const float* sa1_w1 = (const float*)d_in[3];
  const float* sa1_b1 = (const float*)d_in[4];
  const float* sa2_w0 = (const float*)d_in[5];
  const float* sa2_b0 = (const float*)d_in[6];
  const float* sa2_w1 = (const float*)d_in[7];
  const float* sa2_b1 = (const float*)d_in[8];
  const float* sa3_w0 = (const float*)d_in[9];
  const float* sa3_b0 = (const float*)d_in[10];
  const float* sa3_w1 = (const float*)d_in[11];
  const float* sa3_b1 = (const float*)d_in[12];
  const float* fp1_w0 = (const float*)d_in[13];
  const float* fp1_b0 = (const float*)d_in[14];
  const float* fp1_w1 = (const float*)d_in[15];
  const float* fp1_b1 = (const float*)d_in[16];
  const float* fp2_w0 = (const float*)d_in[17];
  const float* fp2_b0 = (const float*)d_in[18];
  const float* fp2_w1 = (const float*)d_in[19];
  const float* fp2_b1 = (const float*)d_in[20];
  const float* fc1_w  = (const float*)d_in[21];
  const float* fc1_b  = (const float*)d_in[22];
  const float* fc2_w  = (const float*)d_in[23];
  const float* fc2_b  = (const float*)d_in[24];
  const float* out_w  = (const float*)d_in[25];
  const float* out_b  = (const float*)d_in[26];
  float* out = (float*)d_out;

  const size_t M = M_ROWS;
  float* ws = (float*)d_ws;
  // fp32 / misc buffers (offsets in floats)
  float* T   = ws;             // [0,256)   MLP temp (fp32 path)
  float* G1  = ws + M * 256;   // [256,320)
  float* X1  = ws + M * 320;   // [320,384)
  float* X2  = ws + M * 384;   // [384,512)
  float* H2  = ws + M * 512;   // [512,640)  sa2 out fp32
  __hip_bfloat16* H3b16 = (__hip_bfloat16*)(ws + M * 640);  // [640,768) sa3 out bf16
  unsigned long long* MASK = (unsigned long long*)(ws + M * 896);  // [896,960)
  __hip_bfloat16* X1b = (__hip_bfloat16*)(ws + M * 960);    // [960,992)
  __hip_bfloat16* X2b = (__hip_bfloat16*)(ws + M * 992);    // [992,1056)
  __hip_bfloat16* TB0 = (__hip_bfloat16*)(ws + M * 1056);   // [1056,1184) sa3 l1 out (M*256)
  __hip_bfloat16* TB1 = (__hip_bfloat16*)(ws + M * 1184);   // [1184,1440) fp1 l1 out (M*512)
  __hip_bfloat16* TB2 = (__hip_bfloat16*)(ws + M * 1440);   // [1440,1568) fp2 l1 out (M*256)
  __hip_bfloat16* G   = (__hip_bfloat16*)(ws + M * 1568);   // [1568,2080) concat (M*1024)
  __hip_bfloat16* H3b = (__hip_bfloat16*)(ws + M * 2080);   // [2080,2208) fc1 out (M*256)
  __hip_bfloat16* WB  = (__hip_bfloat16*)(ws + M * 2208);   // weights (~802816 bf16)
  if (ws_size < (size_t)M * 2240 * sizeof(float)) return;
  __hip_bfloat16* w_sa3_0 = WB;               // 256x128
  __hip_bfloat16* w_sa3_1 = w_sa3_0 + 32768;  // 256x256
  __hip_bfloat16* w_fp1_0 = w_sa3_1 + 65536;  // 512x128
  __hip_bfloat16* w_fp1_1 = w_fp1_0 + 65536;  // 512x512
  __hip_bfloat16* w_fp2_0 = w_fp1_1 + 262144; // 256x64
  __hip_bfloat16* w_fp2_1 = w_fp2_0 + 16384;  // 256x256
  __hip_bfloat16* w_fc1   = w_fp2_1 + 65536;  // 256x1024
  __hip_bfloat16* w_fc2   = w_fc1 + 262144;   // 128x256

  dim3 blk(256);
  TJobs jb;
  const float* srcs[8] = {sa3_w0, sa3_w1, fp1_w0, fp1_w1, fp2_w0, fp2_w1, fc1_w, fc2_w};
  __hip_bfloat16* dsts[8] = {w_sa3_0, w_sa3_1, w_fp1_0, w_fp1_1, w_fp2_0, w_fp2_1, w_fc1, w_fc2};
  int Ks[8] = {128, 256, 128, 512, 64, 256, 1024, 256};
  int Ns[8] = {256, 256, 512, 512, 256, 256, 256, 128};
  int off = 0;
  for (int i = 0; i < 8; i++) {
    jb.W[i] = srcs[i]; jb.Wt[i] = dsts[i];
    jb.K[i] = Ks[i]; jb.N[i] = Ns[i];
    jb.bx[i] = Ns[i] >> 5;
    jb.off[i] = off;
    off += (Ns[i] >> 5) * (Ks[i] >> 5);
  }
  transpose_cast_all<<<off, blk, 0, stream>>>(jb);

  // SA1 (fp32 exact).
  gemm_bias_relu<<<dim3(1, 256), blk, 0, stream>>>(x, 2, sa1_w0, sa1_b0, T, 64, 64, 2);
  gemm_bias_relu<<<dim3(1, 256), blk, 0, stream>>>(T, 64, sa1_w1, sa1_b1, G1, 64, 64, 64);
  knn_mean_kernel<<<16384, 256, 0, stream>>>(x, G1, X1, X1b);
  // SA2 (fp32 exact) + ball64 + gather2.
  gemm_bias_relu<<<dim3(2, 256), blk, 0, stream>>>(X1, 64, sa2_w0, sa2_b0, T, 128, 128, 64);
  gemm_bias_relu<<<dim3(2, 256), blk, 0, stream>>>(T, 128, sa2_w1, sa2_b1, H2, 128, 128, 128);
  ball_mask_sym<64><<<dim3(136, 8), blk, 0, stream>>>(X1, MASK, 0.2f * 0.2f);
  ball_gather_kernel<float><<<16384, 128, 0, stream>>>(MASK, H2, 128, X2, X2b, 128, 32);
  // ball128 (needs only X2), then the fused layer-1 and layer-2 GEMM triples.
  ball_mask_sym<128><<<dim3(136, 8), blk, 0, stream>>>(X2, MASK, 0.4f * 0.4f);
  {
    GJobs g1;
    g1.A[0] = (const short*)X2b; g1.W[0] = (const short*)w_sa3_0; g1.bias[0] = sa3_b0;
    g1.Y[0] = TB0; g1.lda[0] = 128; g1.ldw[0] = 128; g1.ldy[0] = 256; g1.N[0] = 256; g1.K[0] = 128;
    g1.A[1] = (const short*)X2b; g1.W[1] = (const short*)w_fp1_0; g1.bias[1] = fp1_b0;
    g1.Y[1] = TB1; g1.lda[1] = 128; g1.ldw[1] = 128; g1.ldy[1] = 512; g1.N[1] = 512; g1.K[1] = 128;
    g1.A[2] = (const short*)X1b; g1.W[2] = (const short*)w_fp2_0; g1.bias[2] = fp2_b0;
    g1.Y[2] = TB2; g1.lda[2] = 64; g1.ldw[2] = 64; g1.ldy[2] = 256; g1.N[2] = 256; g1.K[2] = 64;
    int tot1 = 0;
    for (int i = 0; i < 3; i++) {
      g1.xt[i] = g1.N[i] >> 7;
      g1.off[i] = tot1;
      tot1 += g1.xt[i] * 128;
    }
    gemm_mfma_multi<<<tot1, blk, 0, stream>>>(g1);

    GJobs g2;
    g2.A[0] = (const short*)TB0; g2.W[0] = (const short*)w_sa3_1; g2.bias[0] = sa3_b1;
    g2.Y[0] = H3b16; g2.lda[0] = 256; g2.ldw[0] = 256; g2.ldy[0] = 256; g2.N[0] = 256; g2.K[0] = 256;
    g2.A[1] = (const short*)TB1; g2.W[1] = (const short*)w_fp1_1; g2.bias[1] = fp1_b1;
    g2.Y[1] = G + 256; g2.lda[1] = 512; g2.ldw[1] = 512; g2.ldy[1] = 1024; g2.N[1] = 512; g2.K[1] = 512;
    g2.A[2] = (const short*)TB2; g2.W[2] = (const short*)w_fp2_1; g2.bias[2] = fp2_b1;
    g2.Y[2] = G; g2.lda[2] = 256; g2.ldw[2] = 256; g2.ldy[2] = 1024; g2.N[2] = 256; g2.K[2] = 256;
    int tot2 = 0;
    for (int i = 0; i < 3; i++) {
      g2.xt[i] = g2.N[i] >> 7;
      g2.off[i] = tot2;
      tot2 += g2.xt[i] * 128;
    }
    gemm_mfma_multi<<<tot2, blk, 0, stream>>>(g2);
  }
  // gather3 fills G[768:1024] from sa3 output.
  ball_gather_kernel<__hip_bfloat16><<<16384, 256, 0, stream>>>(MASK, H3b16, 256, nullptr, G + 768, 1024, 64);
  // Head: fc1 (bf16), then fc2+out fused.
  gemm_mfma<true><<<dim3(2, 128), blk, 0, stream>>>(G, 1024, w_fc1, 1024, fc1_b, H3b, 256, 256, 1024);
  gemm_fc2_out<<<dim3(1, 128), blk, 0, stream>>>(H3b, w_fc2, fc2_b, out_w, out_b, out);
}